// Round 1
// baseline (312.841 us; speedup 1.0000x reference)
//
#include <hip/hip_runtime.h>
#include <cstddef>
#include <cstdint>

// Segment-wise softmax (torch_geometric.utils.softmax semantics).
// x: [N, 128] fp32, batch: [N] sorted int32 segment ids in [0, 2048).
// out[i,h] = exp(x[i,h] - segmax[b,h]) / (segsum[b,h] + 1e-16), b = batch[i].

constexpr int H    = 128;   // feature dim
constexpr int H4   = 32;    // float4s per row
constexpr int NSEG = 2048;  // NUM_SEGMENTS
constexpr float EPSF = 1e-16f;

// ---------------------------------------------------------------------------
// Kernel 1: per-segment online max + sum(exp(x-max)) per column.
// One block per segment; batch is sorted so the segment is a contiguous row
// range found by binary search. 256 threads: thread t owns float4-column
// (t & 31) and row-stripe (t >> 5) of 8; partials combined via LDS.
// ---------------------------------------------------------------------------
__global__ __launch_bounds__(256) void seg_stats(const float* __restrict__ x,
                                                 const int* __restrict__ batch,
                                                 int N,
                                                 float* __restrict__ m_tab,
                                                 float* __restrict__ r_tab) {
  __shared__ int sh_bounds[2];
  __shared__ float sh_m[8][H];
  __shared__ float sh_s[8][H];
  const int seg = blockIdx.x;

  if (threadIdx.x == 0) {
    // lower_bound(batch, seg) and lower_bound(batch, seg+1)
    int lo = 0, hi = N;
    while (lo < hi) { int mid = (lo + hi) >> 1; if (batch[mid] < seg) lo = mid + 1; else hi = mid; }
    sh_bounds[0] = lo;
    hi = N;
    while (lo < hi) { int mid = (lo + hi) >> 1; if (batch[mid] <= seg) lo = mid + 1; else hi = mid; }
    sh_bounds[1] = lo;
  }
  __syncthreads();
  const int start = sh_bounds[0];
  const int end   = sh_bounds[1];

  const int c4  = threadIdx.x & 31;  // which float4 of the row
  const int sub = threadIdx.x >> 5;  // row stripe 0..7
  const float4* __restrict__ x4 = reinterpret_cast<const float4*>(x);

  float m[4] = {-INFINITY, -INFINITY, -INFINITY, -INFINITY};
  float s[4] = {0.f, 0.f, 0.f, 0.f};

  for (int r = start + sub; r < end; r += 8) {
    const float4 v4 = x4[(size_t)r * H4 + c4];
    const float v[4] = {v4.x, v4.y, v4.z, v4.w};
#pragma unroll
    for (int j = 0; j < 4; ++j) {
      if (v[j] > m[j]) {           // rare rescale path (max grows ~log(n) times)
        s[j] *= __expf(m[j] - v[j]);  // first hit: exp(-inf)=0 zeroes the dummy
        m[j] = v[j];
      }
      s[j] += __expf(v[j] - m[j]);
    }
  }

#pragma unroll
  for (int j = 0; j < 4; ++j) {
    sh_m[sub][c4 * 4 + j] = m[j];
    sh_s[sub][c4 * 4 + j] = s[j];
  }
  __syncthreads();

  if (threadIdx.x < H) {
    const int col = threadIdx.x;
    float M = sh_m[0][col];
    float S = sh_s[0][col];
#pragma unroll
    for (int k = 1; k < 8; ++k) {
      const float mi = sh_m[k][col];
      const float si = sh_s[k][col];
      const float nM = fmaxf(M, mi);
      const float wa = (M  == -INFINITY) ? 0.f : __expf(M  - nM);
      const float wb = (mi == -INFINITY) ? 0.f : __expf(mi - nM);
      S = S * wa + si * wb;
      M = nM;
    }
    if (M == -INFINITY) M = 0.f;  // empty segment: mirror reference's finite-fix
    m_tab[(size_t)seg * H + col] = M;
    r_tab[(size_t)seg * H + col] = 1.0f / (S + EPSF);
  }
}

// ---------------------------------------------------------------------------
// Kernel 2: out = exp(x - m[batch]) * rinv[batch], float4 grid-stride.
// Tables are 2 MB (L2-resident); batch is sorted so table gathers are
// effectively sequential.
// ---------------------------------------------------------------------------
__global__ __launch_bounds__(256) void seg_norm(const float* __restrict__ x,
                                                const int* __restrict__ batch,
                                                size_t N,
                                                const float* __restrict__ m_tab,
                                                const float* __restrict__ r_tab,
                                                float* __restrict__ out) {
  const float4* __restrict__ x4 = reinterpret_cast<const float4*>(x);
  const float4* __restrict__ m4 = reinterpret_cast<const float4*>(m_tab);
  const float4* __restrict__ r4 = reinterpret_cast<const float4*>(r_tab);
  float4* __restrict__ out4 = reinterpret_cast<float4*>(out);

  const size_t total  = N * (size_t)H4;
  const size_t stride = (size_t)gridDim.x * blockDim.x;
  for (size_t idx = (size_t)blockIdx.x * blockDim.x + threadIdx.x; idx < total;
       idx += stride) {
    const size_t row = idx >> 5;
    const int c4 = (int)(idx & 31);
    const int b = batch[row];
    const float4 v  = x4[idx];
    const float4 mm = m4[(size_t)b * H4 + c4];
    const float4 rr = r4[(size_t)b * H4 + c4];
    float4 o;
    o.x = __expf(v.x - mm.x) * rr.x;
    o.y = __expf(v.y - mm.y) * rr.y;
    o.z = __expf(v.z - mm.z) * rr.z;
    o.w = __expf(v.w - mm.w) * rr.w;
    out4[idx] = o;
  }
}

extern "C" void kernel_launch(void* const* d_in, const int* in_sizes, int n_in,
                              void* d_out, int out_size, void* d_ws, size_t ws_size,
                              hipStream_t stream) {
  const float* x   = (const float*)d_in[0];
  const int* batch = (const int*)d_in[1];
  const int N = in_sizes[1];  // rows; in_sizes[0] == N*H

  float* m_tab = (float*)d_ws;                       // [NSEG][H]  (1 MB)
  float* r_tab = m_tab + (size_t)NSEG * H;           // [NSEG][H]  (1 MB)

  seg_stats<<<NSEG, 256, 0, stream>>>(x, batch, N, m_tab, r_tab);
  seg_norm<<<2048, 256, 0, stream>>>(x, batch, (size_t)N, m_tab, r_tab,
                                     (float*)d_out);
}

// Round 2
// 295.524 us; speedup vs baseline: 1.0586x; 1.0586x over previous
//
#include <hip/hip_runtime.h>
#include <cstddef>
#include <cstdint>

// Segment-wise softmax (torch_geometric.utils.softmax semantics), FUSED.
// x: [N, 128] fp32, batch: [N] sorted int32 segment ids in [0, 2048).
// out[i,h] = exp(x[i,h] - segmax[b,h]) / (segsum[b,h] + 1e-16), b = batch[i].
//
// One block per segment (batch sorted -> contiguous row range via binary
// search). Pass A: online per-column max + sum(exp) over the segment's rows.
// Pass B: immediately re-read the same ~250 KB (L2/L3-resident, since the
// concurrent working set is ~16-32 MB << 256 MB Infinity Cache) and write
// normalized output. HBM traffic ~1.02 GB vs 1.5 GB for the 2-kernel version.

constexpr int H    = 128;   // feature dim
constexpr int H4   = 32;    // float4s per row
constexpr int NSEG = 2048;  // NUM_SEGMENTS
constexpr float EPSF = 1e-16f;

__global__ __launch_bounds__(256) void seg_softmax_fused(
    const float* __restrict__ x,
    const int* __restrict__ batch,
    int N,
    float* __restrict__ out) {
  __shared__ int sh_bounds[2];
  __shared__ float sh_m[8][H];
  __shared__ float sh_s[8][H];
  __shared__ float sh_M[H];   // final per-column max
  __shared__ float sh_R[H];   // final per-column 1/(sum+eps)
  const int seg = blockIdx.x;

  if (threadIdx.x == 0) {
    // lower_bound(batch, seg) and lower_bound(batch, seg+1)
    int lo = 0, hi = N;
    while (lo < hi) { int mid = (lo + hi) >> 1; if (batch[mid] < seg) lo = mid + 1; else hi = mid; }
    sh_bounds[0] = lo;
    hi = N;
    while (lo < hi) { int mid = (lo + hi) >> 1; if (batch[mid] <= seg) lo = mid + 1; else hi = mid; }
    sh_bounds[1] = lo;
  }
  __syncthreads();
  const int start = sh_bounds[0];
  const int end   = sh_bounds[1];

  const int c4  = threadIdx.x & 31;  // which float4 of the row
  const int sub = threadIdx.x >> 5;  // row stripe 0..7
  const float4* __restrict__ x4 = reinterpret_cast<const float4*>(x);
  float4* __restrict__ out4 = reinterpret_cast<float4*>(out);

  // ---- Pass A: online max + sum(exp(x-max)) per column ----
  float m[4] = {-INFINITY, -INFINITY, -INFINITY, -INFINITY};
  float s[4] = {0.f, 0.f, 0.f, 0.f};

  for (int r = start + sub; r < end; r += 8) {
    const float4 v4 = x4[(size_t)r * H4 + c4];
    const float v[4] = {v4.x, v4.y, v4.z, v4.w};
#pragma unroll
    for (int j = 0; j < 4; ++j) {
      if (v[j] > m[j]) {              // rare rescale path
        s[j] *= __expf(m[j] - v[j]);  // first hit: exp(-inf)=0 zeroes the dummy
        m[j] = v[j];
      }
      s[j] += __expf(v[j] - m[j]);
    }
  }

#pragma unroll
  for (int j = 0; j < 4; ++j) {
    sh_m[sub][c4 * 4 + j] = m[j];
    sh_s[sub][c4 * 4 + j] = s[j];
  }
  __syncthreads();

  if (threadIdx.x < H) {
    const int col = threadIdx.x;
    float M = sh_m[0][col];
    float S = sh_s[0][col];
#pragma unroll
    for (int k = 1; k < 8; ++k) {
      const float mi = sh_m[k][col];
      const float si = sh_s[k][col];
      const float nM = fmaxf(M, mi);
      const float wa = (M  == -INFINITY) ? 0.f : __expf(M  - nM);
      const float wb = (mi == -INFINITY) ? 0.f : __expf(mi - nM);
      S = S * wa + si * wb;
      M = nM;
    }
    if (M == -INFINITY) M = 0.f;  // empty segment: mirror reference's finite-fix
    sh_M[col] = M;
    sh_R[col] = 1.0f / (S + EPSF);
  }
  __syncthreads();

  // ---- Pass B: normalize; rows are hot in L2/L3 from pass A ----
  const float4 mm = *reinterpret_cast<const float4*>(&sh_M[c4 * 4]);
  const float4 rr = *reinterpret_cast<const float4*>(&sh_R[c4 * 4]);

  for (int r = start + sub; r < end; r += 8) {
    const size_t idx = (size_t)r * H4 + c4;
    const float4 v = x4[idx];
    float4 o;
    o.x = __expf(v.x - mm.x) * rr.x;
    o.y = __expf(v.y - mm.y) * rr.y;
    o.z = __expf(v.z - mm.z) * rr.z;
    o.w = __expf(v.w - mm.w) * rr.w;
    out4[idx] = o;
  }
}

extern "C" void kernel_launch(void* const* d_in, const int* in_sizes, int n_in,
                              void* d_out, int out_size, void* d_ws, size_t ws_size,
                              hipStream_t stream) {
  const float* x   = (const float*)d_in[0];
  const int* batch = (const int*)d_in[1];
  const int N = in_sizes[1];  // rows; in_sizes[0] == N*H

  seg_softmax_fused<<<NSEG, 256, 0, stream>>>(x, batch, N, (float*)d_out);
}

// Round 4
// 257.706 us; speedup vs baseline: 1.2139x; 1.1468x over previous
//
#include <hip/hip_runtime.h>
#include <cstddef>
#include <cstdint>

// Segment-wise softmax (torch_geometric.utils.softmax semantics), FUSED,
// unrolled x4 for memory-level parallelism.
// x: [N, 128] fp32, batch: [N] sorted int32 segment ids in [0, 2048).
// out[i,h] = exp(x[i,h] - segmax[b,h]) / (segsum[b,h] + 1e-16), b = batch[i].

constexpr int H    = 128;   // feature dim
constexpr int H4   = 32;    // float4s per row
constexpr int NSEG = 2048;  // NUM_SEGMENTS
constexpr float EPSF = 1e-16f;

// clang-native 16B vector (HIP's float4 is a class; nontemporal builtin
// requires a real vector type)
typedef float vfloat4 __attribute__((ext_vector_type(4)));

__global__ __launch_bounds__(256) void seg_softmax_fused(
    const float* __restrict__ x,
    const int* __restrict__ batch,
    int N,
    float* __restrict__ out) {
  __shared__ int sh_bounds[2];
  __shared__ float sh_m[8][H];
  __shared__ float sh_s[8][H];
  __shared__ float sh_M[H];   // final per-column max
  __shared__ float sh_R[H];   // final per-column 1/(sum+eps)
  const int seg = blockIdx.x;

  if (threadIdx.x == 0) {
    int lo = 0, hi = N;
    while (lo < hi) { int mid = (lo + hi) >> 1; if (batch[mid] < seg) lo = mid + 1; else hi = mid; }
    sh_bounds[0] = lo;
    hi = N;
    while (lo < hi) { int mid = (lo + hi) >> 1; if (batch[mid] <= seg) lo = mid + 1; else hi = mid; }
    sh_bounds[1] = lo;
  }
  __syncthreads();
  const int start = sh_bounds[0];
  const int end   = sh_bounds[1];

  const int c4  = threadIdx.x & 31;  // which float4 of the row
  const int sub = threadIdx.x >> 5;  // row stripe 0..7
  const vfloat4* __restrict__ x4 = reinterpret_cast<const vfloat4*>(x);
  vfloat4* __restrict__ out4 = reinterpret_cast<vfloat4*>(out);

  // ---- Pass A: online max + sum(exp(x-max)) per column, unrolled x4 ----
  float m[4] = {-INFINITY, -INFINITY, -INFINITY, -INFINITY};
  float s[4] = {0.f, 0.f, 0.f, 0.f};

  int r = start + sub;
  for (; r + 24 < end; r += 32) {
    // 4 independent loads in flight
    const vfloat4 a = x4[(size_t)r        * H4 + c4];
    const vfloat4 b = x4[(size_t)(r +  8) * H4 + c4];
    const vfloat4 c = x4[(size_t)(r + 16) * H4 + c4];
    const vfloat4 d = x4[(size_t)(r + 24) * H4 + c4];
#pragma unroll
    for (int j = 0; j < 4; ++j) {
      const float bm = fmaxf(fmaxf(a[j], b[j]), fmaxf(c[j], d[j]));
      if (bm > m[j]) {                 // one rescale test per 4 rows
        s[j] *= __expf(m[j] - bm);     // first hit: exp(-inf)=0 zeroes dummy
        m[j] = bm;
      }
      s[j] += __expf(a[j] - m[j]) + __expf(b[j] - m[j]) +
              __expf(c[j] - m[j]) + __expf(d[j] - m[j]);
    }
  }
  for (; r < end; r += 8) {
    const vfloat4 v = x4[(size_t)r * H4 + c4];
#pragma unroll
    for (int j = 0; j < 4; ++j) {
      if (v[j] > m[j]) { s[j] *= __expf(m[j] - v[j]); m[j] = v[j]; }
      s[j] += __expf(v[j] - m[j]);
    }
  }

#pragma unroll
  for (int j = 0; j < 4; ++j) {
    sh_m[sub][c4 * 4 + j] = m[j];
    sh_s[sub][c4 * 4 + j] = s[j];
  }
  __syncthreads();

  if (threadIdx.x < H) {
    const int col = threadIdx.x;
    float M = sh_m[0][col];
    float S = sh_s[0][col];
#pragma unroll
    for (int k = 1; k < 8; ++k) {
      const float mi = sh_m[k][col];
      const float si = sh_s[k][col];
      const float nM = fmaxf(M, mi);
      const float wa = (M  == -INFINITY) ? 0.f : __expf(M  - nM);
      const float wb = (mi == -INFINITY) ? 0.f : __expf(mi - nM);
      S = S * wa + si * wb;
      M = nM;
    }
    if (M == -INFINITY) M = 0.f;  // empty segment: mirror reference's finite-fix
    sh_M[col] = M;
    sh_R[col] = 1.0f / (S + EPSF);
  }
  __syncthreads();

  // ---- Pass B: normalize (reads are L2/L3-hot from pass A), unrolled x4 ----
  const float mmx = sh_M[c4 * 4 + 0], mmy = sh_M[c4 * 4 + 1],
              mmz = sh_M[c4 * 4 + 2], mmw = sh_M[c4 * 4 + 3];
  const float rrx = sh_R[c4 * 4 + 0], rry = sh_R[c4 * 4 + 1],
              rrz = sh_R[c4 * 4 + 2], rrw = sh_R[c4 * 4 + 3];

  auto norm1 = [&](const vfloat4 v) {
    vfloat4 o;
    o.x = __expf(v.x - mmx) * rrx;
    o.y = __expf(v.y - mmy) * rry;
    o.z = __expf(v.z - mmz) * rrz;
    o.w = __expf(v.w - mmw) * rrw;
    return o;
  };

  r = start + sub;
  for (; r + 24 < end; r += 32) {
    const size_t i0 = (size_t)r        * H4 + c4;
    const size_t i1 = (size_t)(r +  8) * H4 + c4;
    const size_t i2 = (size_t)(r + 16) * H4 + c4;
    const size_t i3 = (size_t)(r + 24) * H4 + c4;
    const vfloat4 a = x4[i0];
    const vfloat4 b = x4[i1];
    const vfloat4 c = x4[i2];
    const vfloat4 d = x4[i3];
    __builtin_nontemporal_store(norm1(a), &out4[i0]);
    __builtin_nontemporal_store(norm1(b), &out4[i1]);
    __builtin_nontemporal_store(norm1(c), &out4[i2]);
    __builtin_nontemporal_store(norm1(d), &out4[i3]);
  }
  for (; r < end; r += 8) {
    const size_t i0 = (size_t)r * H4 + c4;
    __builtin_nontemporal_store(norm1(x4[i0]), &out4[i0]);
  }
}

extern "C" void kernel_launch(void* const* d_in, const int* in_sizes, int n_in,
                              void* d_out, int out_size, void* d_ws, size_t ws_size,
                              hipStream_t stream) {
  const float* x   = (const float*)d_in[0];
  const int* batch = (const int*)d_in[1];
  const int N = in_sizes[1];  // rows; in_sizes[0] == N*H

  seg_softmax_fused<<<NSEG, 256, 0, stream>>>(x, batch, N, (float*)d_out);
}